// Round 5
// baseline (11.751 us; speedup 1.0000x reference)
//
#include <hip/hip_runtime.h>

// Problem constants (from reference): x,y are [B,C,H,W] fp32
constexpr int Bn = 8, Cn = 2, Hn = 256, Wn = 4096;
constexpr long long NTOT = (long long)Bn * Cn * Hn * Wn;   // 16,777,216
constexpr int ROWS   = Bn * Cn * Hn;                        // 4096
constexpr int NBLK1  = 2048;                                // stage-1 blocks
constexpr int THREADS = 256;
constexpr int TOTTHR = NBLK1 * THREADS;                     // 524,288 threads

// Stage 1, fast path (w==1024): the masked region is ROWS x 256 float4-groups
// (aligned to s4 = s & ~3). Thread (blk,tid) handles local group `loc` of two
// rows 2048 apart (same loc since TOTTHR = 2048 rows * 256 groups). All 4
// 16B loads are issued into named registers before any compute. Thread with
// loc==0 fixes up the head-excluded / tail-included elements (head in 0..3).
// 2048 blocks = 8 blocks/CU = 32 waves/CU (full occupancy, VGPR<=64).
__global__ __launch_bounds__(THREADS, 8)
void masked_mse_partial_kernel(const float* __restrict__ x,
                               const float* __restrict__ y,
                               const int* __restrict__ mask_pos,
                               const int* __restrict__ mask_width,
                               float* __restrict__ partial) {
    const int tid = threadIdx.x;
    const int gt  = blockIdx.x * THREADS + tid;   // 0 .. TOTTHR-1
    const int w   = mask_width[0];

    float acc = 0.0f;

    if (w == 1024) {
        const int loc  = gt & 255;                // local float4-group in row
        const int row0 = gt >> 8;                 // 0..2047
        const int row1 = row0 + 2048;             // 2048..4095
        const int b0   = row0 >> 9;               // Cn*Hn = 512 rows/batch
        const int b1   = b0 + 4;

        int s0 = mask_pos[b0]; s0 = s0 < 0 ? 0 : (s0 > 3072 ? 3072 : s0);
        int s1 = mask_pos[b1]; s1 = s1 < 0 ? 0 : (s1 > 3072 ? 3072 : s1);
        const int s40 = s0 & ~3, h0 = s0 - s40;
        const int s41 = s1 & ~3, h1 = s1 - s41;

        const float* __restrict__ xr0 = x + (size_t)row0 * Wn + s40 + 4 * loc;
        const float* __restrict__ yr0 = y + (size_t)row0 * Wn + s40 + 4 * loc;
        const float* __restrict__ xr1 = x + (size_t)row1 * Wn + s41 + 4 * loc;
        const float* __restrict__ yr1 = y + (size_t)row1 * Wn + s41 + 4 * loc;

        // issue all 4 independent 16B loads before any compute
        const float4 xa = *(const float4*)xr0;
        const float4 ya = *(const float4*)yr0;
        const float4 xb = *(const float4*)xr1;
        const float4 yb = *(const float4*)yr1;

        float a0 = xa.x - ya.x, a1 = xa.y - ya.y, a2 = xa.z - ya.z, a3 = xa.w - ya.w;
        float c0 = xb.x - yb.x, c1 = xb.y - yb.y, c2 = xb.z - yb.z, c3 = xb.w - yb.w;

        if (loc == 0) {                           // boundary fixups (cold)
            if (h0) {
                a0 = 0.0f;
                if (h0 > 1) a1 = 0.0f;
                if (h0 > 2) a2 = 0.0f;
                const float4 xt = *(const float4*)(xr0 + 1024);
                const float4 yt = *(const float4*)(yr0 + 1024);
                const float t0 = xt.x - yt.x, t1 = xt.y - yt.y, t2 = xt.z - yt.z;
                acc += t0 * t0;
                if (h0 > 1) acc += t1 * t1;
                if (h0 > 2) acc += t2 * t2;
            }
            if (h1) {
                c0 = 0.0f;
                if (h1 > 1) c1 = 0.0f;
                if (h1 > 2) c2 = 0.0f;
                const float4 xt = *(const float4*)(xr1 + 1024);
                const float4 yt = *(const float4*)(yr1 + 1024);
                const float t0 = xt.x - yt.x, t1 = xt.y - yt.y, t2 = xt.z - yt.z;
                acc += t0 * t0;
                if (h1 > 1) acc += t1 * t1;
                if (h1 > 2) acc += t2 * t2;
            }
        }

        acc += a0 * a0 + a1 * a1 + a2 * a2 + a3 * a3;
        acc += c0 * c0 + c1 * c1 + c2 * c2 + c3 * c3;
    } else {
        // ---- generic fallback (never hit in this bench) ----
        const int smaxg = Wn - w;
        const int G = (w + 6) >> 2;               // padded groups per row
        const long long total = (long long)ROWS * G;
        for (long long g = gt; g < total; g += TOTTHR) {
            const int row  = (int)(g / G);
            const int locg = (int)(g % G);
            const int b    = row >> 9;
            int s = mask_pos[b]; s = s < 0 ? 0 : (s > smaxg ? smaxg : s);
            const int e  = s + w;
            const int s4 = s & ~3;
            const int e4 = (e + 3) & ~3;
            const int col = s4 + 4 * locg;
            if (col >= e4) continue;
            const float4 xv = *(const float4*)(x + (size_t)row * Wn + col);
            const float4 yv = *(const float4*)(y + (size_t)row * Wn + col);
            const float d0 = xv.x - yv.x;
            const float d1 = xv.y - yv.y;
            const float d2 = xv.z - yv.z;
            const float d3 = xv.w - yv.w;
            if (col + 0 >= s && col + 0 < e) acc += d0 * d0;
            if (col + 1 >= s && col + 1 < e) acc += d1 * d1;
            if (col + 2 >= s && col + 2 < e) acc += d2 * d2;
            if (col + 3 >= s && col + 3 < e) acc += d3 * d3;
        }
    }

    // wave-64 butterfly reduce
    #pragma unroll
    for (int off = 32; off > 0; off >>= 1)
        acc += __shfl_down(acc, off, 64);

    __shared__ float wsum[4];
    const int lane = tid & 63;
    const int wid  = tid >> 6;
    if (lane == 0) wsum[wid] = acc;
    __syncthreads();

    if (tid == 0)
        partial[blockIdx.x] = wsum[0] + wsum[1] + wsum[2] + wsum[3];
}

// Stage 2: one block sums NBLK1 float partials (float4-vectorized) in double.
__global__ __launch_bounds__(THREADS)
void masked_mse_final_kernel(const float* __restrict__ partial,
                             float* __restrict__ out) {
    const float4 v0 = ((const float4*)partial)[threadIdx.x];        // 0..255
    const float4 v1 = ((const float4*)partial)[threadIdx.x + 256];  // 256..511
    double acc = (double)v0.x + (double)v0.y + (double)v0.z + (double)v0.w
               + (double)v1.x + (double)v1.y + (double)v1.z + (double)v1.w;

    #pragma unroll
    for (int off = 32; off > 0; off >>= 1)
        acc += __shfl_down(acc, off, 64);

    __shared__ double wsum[4];
    const int lane = threadIdx.x & 63;
    const int wid  = threadIdx.x >> 6;
    if (lane == 0) wsum[wid] = acc;
    __syncthreads();

    if (threadIdx.x == 0) {
        const double total = wsum[0] + wsum[1] + wsum[2] + wsum[3];
        out[0] = (float)(total / (double)NTOT);
    }
}

extern "C" void kernel_launch(void* const* d_in, const int* in_sizes, int n_in,
                              void* d_out, int out_size, void* d_ws, size_t ws_size,
                              hipStream_t stream) {
    const float* x          = (const float*)d_in[0];
    const float* y          = (const float*)d_in[1];
    const int*   mask_pos   = (const int*)d_in[2];
    const int*   mask_width = (const int*)d_in[3];
    float*       out        = (float*)d_out;
    float*       partial    = (float*)d_ws;   // NBLK1 floats = 8 KB scratch

    masked_mse_partial_kernel<<<NBLK1, THREADS, 0, stream>>>(x, y, mask_pos, mask_width, partial);
    masked_mse_final_kernel<<<1, THREADS, 0, stream>>>(partial, out);
}